// Round 8
// baseline (2766.232 us; speedup 1.0000x reference)
//
#include <hip/hip_runtime.h>
#include <cstdint>

#define NLEV 16
#define HMAP (1u << 19)
#define HMASK (HMAP - 1u)
#define NBKT 32768

typedef float f32x2 __attribute__((ext_vector_type(2)));

// res[l] = int(16 * 1.5**l), exact in double
__device__ __constant__ int RES_C[NLEV] = {16, 24, 36, 54, 81, 121, 182, 273,
                                           410, 615, 922, 1383, 2075, 3113, 4670, 7006};

// ---- static task schedule: (level, slice-of-16) -> XCD ----
// cost units/slice (est, after Morton-32 sort): L7:32 L6:18.7 L5:6.8 L4:2.75
// L3:1.25 L2:.63 L1:.5 L0:.5 ; hi levels 8-15: 32/slice. Per-XCD ~630-643.
__device__ __constant__ uint8_t TASK_LVL[256] = {
  // X0 (20): L8 x16, L7 s0-3
  8,8,8,8,8,8,8,8,8,8,8,8,8,8,8,8, 7,7,7,7,
  // X1 (20): L9 x16, L7 s4-7
  9,9,9,9,9,9,9,9,9,9,9,9,9,9,9,9, 7,7,7,7,
  // X2 (20): L10 x16, L7 s8-11
  10,10,10,10,10,10,10,10,10,10,10,10,10,10,10,10, 7,7,7,7,
  // X3 (20): L11 x16, L7 s12-15
  11,11,11,11,11,11,11,11,11,11,11,11,11,11,11,11, 7,7,7,7,
  // X4 (23): L12 x16, L6 s0-6
  12,12,12,12,12,12,12,12,12,12,12,12,12,12,12,12, 6,6,6,6,6,6,6,
  // X5 (23): L13 x16, L6 s7-13
  13,13,13,13,13,13,13,13,13,13,13,13,13,13,13,13, 6,6,6,6,6,6,6,
  // X6 (34): L14 x16, L6 s14-15, L5 s0-7, L4 s0-7
  14,14,14,14,14,14,14,14,14,14,14,14,14,14,14,14, 6,6,
  5,5,5,5,5,5,5,5, 4,4,4,4,4,4,4,4,
  // X7 (96): L15 x16, L5 s8-15, L4 s8-15, L3 x16, L2 x16, L1 x16, L0 x16
  15,15,15,15,15,15,15,15,15,15,15,15,15,15,15,15,
  5,5,5,5,5,5,5,5, 4,4,4,4,4,4,4,4,
  3,3,3,3,3,3,3,3,3,3,3,3,3,3,3,3,
  2,2,2,2,2,2,2,2,2,2,2,2,2,2,2,2,
  1,1,1,1,1,1,1,1,1,1,1,1,1,1,1,1,
  0,0,0,0,0,0,0,0,0,0,0,0,0,0,0,0
};
__device__ __constant__ uint8_t TASK_SLC[256] = {
  0,1,2,3,4,5,6,7,8,9,10,11,12,13,14,15, 0,1,2,3,
  0,1,2,3,4,5,6,7,8,9,10,11,12,13,14,15, 4,5,6,7,
  0,1,2,3,4,5,6,7,8,9,10,11,12,13,14,15, 8,9,10,11,
  0,1,2,3,4,5,6,7,8,9,10,11,12,13,14,15, 12,13,14,15,
  0,1,2,3,4,5,6,7,8,9,10,11,12,13,14,15, 0,1,2,3,4,5,6,
  0,1,2,3,4,5,6,7,8,9,10,11,12,13,14,15, 7,8,9,10,11,12,13,
  0,1,2,3,4,5,6,7,8,9,10,11,12,13,14,15, 14,15,
  0,1,2,3,4,5,6,7, 0,1,2,3,4,5,6,7,
  0,1,2,3,4,5,6,7,8,9,10,11,12,13,14,15,
  8,9,10,11,12,13,14,15, 8,9,10,11,12,13,14,15,
  0,1,2,3,4,5,6,7,8,9,10,11,12,13,14,15,
  0,1,2,3,4,5,6,7,8,9,10,11,12,13,14,15,
  0,1,2,3,4,5,6,7,8,9,10,11,12,13,14,15,
  0,1,2,3,4,5,6,7,8,9,10,11,12,13,14,15
};
__device__ __constant__ int XCD_START[9] = {0,20,40,60,80,103,126,160,256};
#define MAX_TASKS 96

// ---- Morton-32 bucket key ----
__device__ __forceinline__ uint32_t part1by2(uint32_t v) {
    v &= 0x1Fu;
    v = (v | (v << 8)) & 0x0000100Fu;
    v = (v | (v << 4)) & 0x000010C3u;
    v = (v | (v << 2)) & 0x00001249u;
    return v;
}

__device__ __forceinline__ uint32_t bucket_of(const float* __restrict__ x, int p) {
    const float HI = (float)(1.0 - 1e-6);
    float px = fminf(fmaxf(x[3 * (size_t)p + 0], 0.0f), HI);
    float py = fminf(fmaxf(x[3 * (size_t)p + 1], 0.0f), HI);
    float pz = fminf(fmaxf(x[3 * (size_t)p + 2], 0.0f), HI);
    uint32_t bx = (uint32_t)(int)(px * 32.0f);
    uint32_t by = (uint32_t)(int)(py * 32.0f);
    uint32_t bz = (uint32_t)(int)(pz * 32.0f);
    return part1by2(bx) | (part1by2(by) << 1) | (part1by2(bz) << 2);
}

// ---- sort passes ----
__global__ __launch_bounds__(256) void k_hist(const float* __restrict__ x,
                                              uint32_t* __restrict__ hist, int n) {
    int i = blockIdx.x * 256 + threadIdx.x;
    const int stride = gridDim.x * 256;
    for (; i < n; i += stride) atomicAdd(&hist[bucket_of(x, i)], 1u);
}

__global__ __launch_bounds__(256) void k_scan(uint32_t* __restrict__ hist) {
    __shared__ uint32_t part[256];
    const int t = threadIdx.x;
    uint32_t s = 0;
    for (int i = t * 128; i < t * 128 + 128; ++i) s += hist[i];
    part[t] = s;
    __syncthreads();
    for (int d = 1; d < 256; d <<= 1) {
        uint32_t w = (t >= d) ? part[t - d] : 0u;
        __syncthreads();
        part[t] += w;
        __syncthreads();
    }
    uint32_t run = part[t] - s;  // exclusive base for this thread's range
    for (int i = t * 128; i < t * 128 + 128; ++i) {
        uint32_t c = hist[i];
        hist[i] = run;
        run += c;
    }
}

__global__ __launch_bounds__(256) void k_scatter(const float* __restrict__ x,
                                                 uint32_t* __restrict__ hist,
                                                 uint32_t* __restrict__ perm, int n) {
    int i = blockIdx.x * 256 + threadIdx.x;
    const int stride = gridDim.x * 256;
    for (; i < n; i += stride) {
        uint32_t pos = atomicAdd(&hist[bucket_of(x, i)], 1u);
        perm[pos] = (uint32_t)i;
    }
}

__global__ __launch_bounds__(256) void k_gatherx(const float* __restrict__ x,
                                                 const uint32_t* __restrict__ perm,
                                                 float* __restrict__ xs, int n) {
    int i = blockIdx.x * 256 + threadIdx.x;
    const int stride = gridDim.x * 256;
    for (; i < n; i += stride) {
        uint32_t p = perm[i];
        xs[3 * (size_t)i + 0] = x[3 * (size_t)p + 0];
        xs[3 * (size_t)i + 1] = x[3 * (size_t)p + 1];
        xs[3 * (size_t)i + 2] = x[3 * (size_t)p + 2];
    }
}

// ---- main encode: 2 sorted positions at one level ----
__device__ __forceinline__ void enc2s(const float* __restrict__ xs,
                                      const uint32_t* __restrict__ perm,
                                      const float2* __restrict__ tl,
                                      float* __restrict__ out,
                                      int lvl, int i0, int i1, int n) {
    const float rf = (float)RES_C[lvl];
    const float HI = (float)(1.0 - 1e-6);

    uint32_t idx[2][8];
    float fx[2], fy[2], fz[2];
    uint32_t prow[2];
    bool valid[2];
    const int iraw[2] = {i0, i1};

    #pragma unroll
    for (int t = 0; t < 2; ++t) {
        int i = iraw[t];
        valid[t] = (i < n);
        i = valid[t] ? i : 0;
        prow[t] = __builtin_nontemporal_load(perm + i);

        float px = __builtin_nontemporal_load(xs + 3 * (size_t)i + 0);
        float py = __builtin_nontemporal_load(xs + 3 * (size_t)i + 1);
        float pz = __builtin_nontemporal_load(xs + 3 * (size_t)i + 2);
        px = fminf(fmaxf(px, 0.0f), HI);
        py = fminf(fmaxf(py, 0.0f), HI);
        pz = fminf(fmaxf(pz, 0.0f), HI);

        const float xsc = px * rf, ysc = py * rf, zsc = pz * rf;
        const float xf = floorf(xsc), yf = floorf(ysc), zf = floorf(zsc);
        fx[t] = xsc - xf;  fy[t] = ysc - yf;  fz[t] = zsc - zf;

        const uint32_t cx = (uint32_t)(int)xf;
        const uint32_t cy = (uint32_t)(int)yf;
        const uint32_t cz = (uint32_t)(int)zf;
        const uint32_t hx[2] = {cx * 73856093u, cx * 73856093u + 73856093u};
        const uint32_t hy[2] = {cy * 19349663u, cy * 19349663u + 19349663u};
        const uint32_t hz[2] = {cz * 83492791u, cz * 83492791u + 83492791u};

        #pragma unroll
        for (int c = 0; c < 8; ++c) {
            const int ox = (c >> 2) & 1;
            const int oy = (c >> 1) & 1;
            const int oz = c & 1;
            idx[t][c] = (hx[ox] ^ hy[oy] ^ hz[oz]) & HMASK;
        }
    }

    float2 v[2][8];
    #pragma unroll
    for (int t = 0; t < 2; ++t)
        #pragma unroll
        for (int c = 0; c < 8; ++c)
            v[t][c] = tl[idx[t][c]];

    #pragma unroll
    for (int t = 0; t < 2; ++t) {
        const float wxa[2] = {1.0f - fx[t], fx[t]};
        const float wya[2] = {1.0f - fy[t], fy[t]};
        const float wza[2] = {1.0f - fz[t], fz[t]};
        float fa = 0.0f, fb = 0.0f;
        #pragma unroll
        for (int c = 0; c < 8; ++c) {
            const int ox = (c >> 2) & 1;
            const int oy = (c >> 1) & 1;
            const int oz = c & 1;
            const float wt = (wxa[ox] * wya[oy]) * wza[oz];
            fa = fmaf(wt, v[t][c].x, fa);
            fb = fmaf(wt, v[t][c].y, fb);
        }
        if (valid[t]) {
            f32x2 ov = {fa, fb};
            f32x2* dst = (f32x2*)(out + (size_t)prow[t] * (NLEV * 2) + lvl * 2);
            __builtin_nontemporal_store(ov, dst);
        }
    }
}

__global__ __launch_bounds__(256, 4)
void hashenc_task(const float* __restrict__ xs, const uint32_t* __restrict__ perm,
                  const float* __restrict__ tables, float* __restrict__ out,
                  int n, int slice_pts, int bpt) {
    const int xcd = (int)(blockIdx.x & 7);
    const int j   = (int)(blockIdx.x >> 3);
    const int tloc = j / bpt;
    const int pos  = j - tloc * bpt;
    const int t0 = XCD_START[xcd];
    if (tloc >= XCD_START[xcd + 1] - t0) return;
    const int lvl = (int)TASK_LVL[t0 + tloc];
    const int slc = (int)TASK_SLC[t0 + tloc];
    const float2* __restrict__ tl = (const float2*)tables + (size_t)lvl * HMAP;
    const int base = slc * slice_pts + pos * 512;
    enc2s(xs, perm, tl, out, lvl, base + (int)threadIdx.x, base + 256 + (int)threadIdx.x, n);
}

// ---- fallback (round-6 structure, identity order) ----
__global__ __launch_bounds__(256, 4)
void hashenc_lvl(const float* __restrict__ x,
                 const float* __restrict__ tables,
                 float* __restrict__ out,
                 int n, int lbase) {
    const int lvl   = lbase + (int)(blockIdx.x & 7);
    const int chunk = (int)(blockIdx.x >> 3);
    const int tid   = (int)threadIdx.x;
    const float rf = (float)RES_C[lvl];
    const float2* __restrict__ tl = (const float2*)tables + (size_t)lvl * HMAP;
    const float HI = (float)(1.0 - 1e-6);

    uint32_t idx[2][8];
    float fx[2], fy[2], fz[2];
    int pidx[2]; bool valid[2];

    #pragma unroll
    for (int t = 0; t < 2; ++t) {
        int p = chunk * 512 + t * 256 + tid;
        valid[t] = (p < n);
        p = p < n ? p : (n - 1);
        pidx[t] = p;
        float px = __builtin_nontemporal_load(x + 3 * (size_t)p + 0);
        float py = __builtin_nontemporal_load(x + 3 * (size_t)p + 1);
        float pz = __builtin_nontemporal_load(x + 3 * (size_t)p + 2);
        px = fminf(fmaxf(px, 0.0f), HI);
        py = fminf(fmaxf(py, 0.0f), HI);
        pz = fminf(fmaxf(pz, 0.0f), HI);
        const float xsc = px * rf, ysc = py * rf, zsc = pz * rf;
        const float xf = floorf(xsc), yf = floorf(ysc), zf = floorf(zsc);
        fx[t] = xsc - xf;  fy[t] = ysc - yf;  fz[t] = zsc - zf;
        const uint32_t cx = (uint32_t)(int)xf;
        const uint32_t cy = (uint32_t)(int)yf;
        const uint32_t cz = (uint32_t)(int)zf;
        const uint32_t hx[2] = {cx * 73856093u, cx * 73856093u + 73856093u};
        const uint32_t hy[2] = {cy * 19349663u, cy * 19349663u + 19349663u};
        const uint32_t hz[2] = {cz * 83492791u, cz * 83492791u + 83492791u};
        #pragma unroll
        for (int c = 0; c < 8; ++c) {
            const int ox = (c >> 2) & 1, oy = (c >> 1) & 1, oz = c & 1;
            idx[t][c] = (hx[ox] ^ hy[oy] ^ hz[oz]) & HMASK;
        }
    }
    float2 v[2][8];
    #pragma unroll
    for (int t = 0; t < 2; ++t)
        #pragma unroll
        for (int c = 0; c < 8; ++c)
            v[t][c] = tl[idx[t][c]];
    #pragma unroll
    for (int t = 0; t < 2; ++t) {
        const float wxa[2] = {1.0f - fx[t], fx[t]};
        const float wya[2] = {1.0f - fy[t], fy[t]};
        const float wza[2] = {1.0f - fz[t], fz[t]};
        float fa = 0.0f, fb = 0.0f;
        #pragma unroll
        for (int c = 0; c < 8; ++c) {
            const int ox = (c >> 2) & 1, oy = (c >> 1) & 1, oz = c & 1;
            const float wt = (wxa[ox] * wya[oy]) * wza[oz];
            fa = fmaf(wt, v[t][c].x, fa);
            fb = fmaf(wt, v[t][c].y, fb);
        }
        if (valid[t]) {
            f32x2 ov = {fa, fb};
            f32x2* dst = (f32x2*)(out + (size_t)pidx[t] * (NLEV * 2) + lvl * 2);
            __builtin_nontemporal_store(ov, dst);
        }
    }
}

extern "C" void kernel_launch(void* const* d_in, const int* in_sizes, int n_in,
                              void* d_out, int out_size, void* d_ws, size_t ws_size,
                              hipStream_t stream) {
    const float* x      = (const float*)d_in[0];
    const float* tables = (const float*)d_in[1];
    float* out          = (float*)d_out;
    const int n = in_sizes[0] / 3;

    const size_t need = (size_t)NBKT * 4 + (size_t)n * 4 + (size_t)n * 12;
    if (n > 0 && ws_size >= need) {
        uint32_t* hist = (uint32_t*)d_ws;
        uint32_t* perm = (uint32_t*)((char*)d_ws + (size_t)NBKT * 4);
        float*    xs   = (float*)((char*)d_ws + (size_t)NBKT * 4 + (size_t)n * 4);

        hipMemsetAsync(hist, 0, (size_t)NBKT * 4, stream);
        hipLaunchKernelGGL(k_hist,    dim3(2048), dim3(256), 0, stream, x, hist, n);
        hipLaunchKernelGGL(k_scan,    dim3(1),    dim3(256), 0, stream, hist);
        hipLaunchKernelGGL(k_scatter, dim3(2048), dim3(256), 0, stream, x, hist, perm, n);
        hipLaunchKernelGGL(k_gatherx, dim3(2048), dim3(256), 0, stream, x, perm, xs, n);

        int slice_pts = (((n + 15) / 16) + 511) / 512 * 512;
        int bpt = slice_pts / 512;
        dim3 grid(8 * MAX_TASKS * bpt);
        hipLaunchKernelGGL(hashenc_task, grid, dim3(256), 0, stream,
                           xs, perm, tables, out, n, slice_pts, bpt);
    } else {
        const int blocks = ((n + 511) / 512) * 8;
        hipLaunchKernelGGL(hashenc_lvl, dim3(blocks), dim3(256), 0, stream,
                           x, tables, out, n, 0);
        hipLaunchKernelGGL(hashenc_lvl, dim3(blocks), dim3(256), 0, stream,
                           x, tables, out, n, 8);
    }
}

// Round 9
// 1973.485 us; speedup vs baseline: 1.4017x; 1.4017x over previous
//
#include <hip/hip_runtime.h>
#include <cstdint>

#define NLEV 16
#define HMAP (1u << 19)
#define HMASK (HMAP - 1u)
#define NBKT 32768
#define LO_LEVELS 6   // levels 0..5 benefit from sorted merging (>=1.2 pts/cell)

typedef float f32x2 __attribute__((ext_vector_type(2)));

// res[l] = int(16 * 1.5**l), exact in double
__device__ __constant__ int RES_C[NLEV] = {16, 24, 36, 54, 81, 121, 182, 273,
                                           410, 615, 922, 1383, 2075, 3113, 4670, 7006};

// ---- Morton-32 bucket key ----
__device__ __forceinline__ uint32_t part1by2(uint32_t v) {
    v &= 0x1Fu;
    v = (v | (v << 8)) & 0x0000100Fu;
    v = (v | (v << 4)) & 0x000010C3u;
    v = (v | (v << 2)) & 0x00001249u;
    return v;
}

__device__ __forceinline__ uint32_t bucket_of(const float* __restrict__ x, int p) {
    const float HI = (float)(1.0 - 1e-6);
    float px = fminf(fmaxf(x[3 * (size_t)p + 0], 0.0f), HI);
    float py = fminf(fmaxf(x[3 * (size_t)p + 1], 0.0f), HI);
    float pz = fminf(fmaxf(x[3 * (size_t)p + 2], 0.0f), HI);
    uint32_t bx = (uint32_t)(int)(px * 32.0f);
    uint32_t by = (uint32_t)(int)(py * 32.0f);
    uint32_t bz = (uint32_t)(int)(pz * 32.0f);
    return part1by2(bx) | (part1by2(by) << 1) | (part1by2(bz) << 2);
}

// ---- sort passes ----
__global__ __launch_bounds__(256) void k_hist(const float* __restrict__ x,
                                              uint32_t* __restrict__ hist, int n) {
    int i = blockIdx.x * 256 + threadIdx.x;
    const int stride = gridDim.x * 256;
    for (; i < n; i += stride) atomicAdd(&hist[bucket_of(x, i)], 1u);
}

__global__ __launch_bounds__(256) void k_scan(uint32_t* __restrict__ hist) {
    __shared__ uint32_t part[256];
    const int t = threadIdx.x;
    uint32_t s = 0;
    for (int i = t * 128; i < t * 128 + 128; ++i) s += hist[i];
    part[t] = s;
    __syncthreads();
    for (int d = 1; d < 256; d <<= 1) {
        uint32_t w = (t >= d) ? part[t - d] : 0u;
        __syncthreads();
        part[t] += w;
        __syncthreads();
    }
    uint32_t run = part[t] - s;  // exclusive base
    for (int i = t * 128; i < t * 128 + 128; ++i) {
        uint32_t c = hist[i];
        hist[i] = run;
        run += c;
    }
}

__global__ __launch_bounds__(256) void k_scatter(const float* __restrict__ x,
                                                 uint32_t* __restrict__ hist,
                                                 uint32_t* __restrict__ perm, int n) {
    int i = blockIdx.x * 256 + threadIdx.x;
    const int stride = gridDim.x * 256;
    for (; i < n; i += stride) {
        uint32_t pos = atomicAdd(&hist[bucket_of(x, i)], 1u);
        perm[pos] = (uint32_t)i;
    }
}

__global__ __launch_bounds__(256) void k_gatherx(const float* __restrict__ x,
                                                 const uint32_t* __restrict__ perm,
                                                 float* __restrict__ xs, int n) {
    int i = blockIdx.x * 256 + threadIdx.x;
    const int stride = gridDim.x * 256;
    for (; i < n; i += stride) {
        uint32_t p = perm[i];
        xs[3 * (size_t)i + 0] = x[3 * (size_t)p + 0];
        xs[3 * (size_t)i + 1] = x[3 * (size_t)p + 1];
        xs[3 * (size_t)i + 2] = x[3 * (size_t)p + 2];
    }
}

// ---- shared encode body: 2 points at one level; row[t] = output row ----
__device__ __forceinline__ void enc2_rows(const float* __restrict__ xsrc,
                                          const float2* __restrict__ tl,
                                          float* __restrict__ out,
                                          int lvl, const int i0, const int i1,
                                          const uint32_t r0, const uint32_t r1,
                                          bool v0, bool v1) {
    const float rf = (float)RES_C[lvl];
    const float HI = (float)(1.0 - 1e-6);  // same double->f32 rounding as JAX

    uint32_t idx[2][8];
    float fx[2], fy[2], fz[2];
    const int ii[2] = {i0, i1};
    const uint32_t rr[2] = {r0, r1};
    const bool vv[2] = {v0, v1};

    #pragma unroll
    for (int t = 0; t < 2; ++t) {
        const int i = ii[t];
        float px = __builtin_nontemporal_load(xsrc + 3 * (size_t)i + 0);
        float py = __builtin_nontemporal_load(xsrc + 3 * (size_t)i + 1);
        float pz = __builtin_nontemporal_load(xsrc + 3 * (size_t)i + 2);
        px = fminf(fmaxf(px, 0.0f), HI);
        py = fminf(fmaxf(py, 0.0f), HI);
        pz = fminf(fmaxf(pz, 0.0f), HI);

        const float xsc = px * rf, ysc = py * rf, zsc = pz * rf;
        const float xf = floorf(xsc), yf = floorf(ysc), zf = floorf(zsc);
        fx[t] = xsc - xf;  fy[t] = ysc - yf;  fz[t] = zsc - zf;

        const uint32_t cx = (uint32_t)(int)xf;
        const uint32_t cy = (uint32_t)(int)yf;
        const uint32_t cz = (uint32_t)(int)zf;
        const uint32_t hx[2] = {cx * 73856093u, cx * 73856093u + 73856093u};
        const uint32_t hy[2] = {cy * 19349663u, cy * 19349663u + 19349663u};
        const uint32_t hz[2] = {cz * 83492791u, cz * 83492791u + 83492791u};

        #pragma unroll
        for (int c = 0; c < 8; ++c) {
            const int ox = (c >> 2) & 1;
            const int oy = (c >> 1) & 1;
            const int oz = c & 1;
            idx[t][c] = (hx[ox] ^ hy[oy] ^ hz[oz]) & HMASK;
        }
    }

    float2 v[2][8];
    #pragma unroll
    for (int t = 0; t < 2; ++t)
        #pragma unroll
        for (int c = 0; c < 8; ++c)
            v[t][c] = tl[idx[t][c]];

    #pragma unroll
    for (int t = 0; t < 2; ++t) {
        const float wxa[2] = {1.0f - fx[t], fx[t]};
        const float wya[2] = {1.0f - fy[t], fy[t]};
        const float wza[2] = {1.0f - fz[t], fz[t]};
        float fa = 0.0f, fb = 0.0f;
        #pragma unroll
        for (int c = 0; c < 8; ++c) {
            const int ox = (c >> 2) & 1;
            const int oy = (c >> 1) & 1;
            const int oz = c & 1;
            const float wt = (wxa[ox] * wya[oy]) * wza[oz];
            fa = fmaf(wt, v[t][c].x, fa);
            fb = fmaf(wt, v[t][c].y, fb);
        }
        if (vv[t]) {
            f32x2 ov = {fa, fb};
            f32x2* dst = (f32x2*)(out + (size_t)rr[t] * (NLEV * 2) + lvl * 2);
            __builtin_nontemporal_store(ov, dst);
        }
    }
}

// Phased hi: levels 6..15, level-major block order. All XCDs work on ONE level
// at a time (each XCD caches its own copy of that level's 4MB table; read-only
// so 8 copies are fine). Unsorted: these resolutions get no merging benefit.
__global__ __launch_bounds__(256, 4)
void hashenc_hi(const float* __restrict__ x,
                const float* __restrict__ tables,
                float* __restrict__ out, int n, int bpl) {
    const int b = (int)blockIdx.x;
    const int lvl = LO_LEVELS + b / bpl;
    const int chunk = b - (lvl - LO_LEVELS) * bpl;
    const int tid = (int)threadIdx.x;
    const float2* __restrict__ tl = (const float2*)tables + (size_t)lvl * HMAP;
    int p0 = chunk * 512 + tid;
    int p1 = p0 + 256;
    const bool v0 = p0 < n, v1 = p1 < n;
    p0 = v0 ? p0 : 0;  p1 = v1 ? p1 : 0;
    enc2_rows(x, tl, out, lvl, p0, p1, (uint32_t)p0, (uint32_t)p1, v0, v1);
}

// Phased lo: levels 0..5 over Morton-sorted points. Same-cell lanes produce
// same corner addresses within each gather instruction -> merged requests.
__global__ __launch_bounds__(256, 4)
void hashenc_lo(const float* __restrict__ xs, const uint32_t* __restrict__ perm,
                const float* __restrict__ tables, float* __restrict__ out,
                int n, int bpl) {
    const int b = (int)blockIdx.x;
    const int lvl = b / bpl;
    const int chunk = b - lvl * bpl;
    const int tid = (int)threadIdx.x;
    const float2* __restrict__ tl = (const float2*)tables + (size_t)lvl * HMAP;
    int i0 = chunk * 512 + tid;
    int i1 = i0 + 256;
    const bool v0 = i0 < n, v1 = i1 < n;
    i0 = v0 ? i0 : 0;  i1 = v1 ? i1 : 0;
    const uint32_t r0 = __builtin_nontemporal_load(perm + i0);
    const uint32_t r1 = __builtin_nontemporal_load(perm + i1);
    enc2_rows(xs, tl, out, lvl, i0, i1, r0, r1, v0, v1);
}

// ---- fallback (round-6 structure) if workspace too small ----
__global__ __launch_bounds__(256, 4)
void hashenc_lvl(const float* __restrict__ x,
                 const float* __restrict__ tables,
                 float* __restrict__ out, int n, int lbase) {
    const int lvl   = lbase + (int)(blockIdx.x & 7);
    const int chunk = (int)(blockIdx.x >> 3);
    const int tid   = (int)threadIdx.x;
    const float2* __restrict__ tl = (const float2*)tables + (size_t)lvl * HMAP;
    int p0 = chunk * 512 + tid;
    int p1 = p0 + 256;
    const bool v0 = p0 < n, v1 = p1 < n;
    p0 = v0 ? p0 : 0;  p1 = v1 ? p1 : 0;
    enc2_rows(x, tl, out, lvl, p0, p1, (uint32_t)p0, (uint32_t)p1, v0, v1);
}

extern "C" void kernel_launch(void* const* d_in, const int* in_sizes, int n_in,
                              void* d_out, int out_size, void* d_ws, size_t ws_size,
                              hipStream_t stream) {
    const float* x      = (const float*)d_in[0];
    const float* tables = (const float*)d_in[1];
    float* out          = (float*)d_out;
    const int n = in_sizes[0] / 3;
    const int bpl = (n + 511) / 512;   // blocks per level (512 pts/block)

    const size_t need = (size_t)NBKT * 4 + (size_t)n * 4 + (size_t)n * 12;
    if (n > 0 && ws_size >= need) {
        uint32_t* hist = (uint32_t*)d_ws;
        uint32_t* perm = (uint32_t*)((char*)d_ws + (size_t)NBKT * 4);
        float*    xs   = (float*)((char*)d_ws + (size_t)NBKT * 4 + (size_t)n * 4);

        // Heavy phased launch first (doesn't depend on sort).
        hipLaunchKernelGGL(hashenc_hi, dim3(bpl * (NLEV - LO_LEVELS)), dim3(256),
                           0, stream, x, tables, out, n, bpl);

        hipMemsetAsync(hist, 0, (size_t)NBKT * 4, stream);
        hipLaunchKernelGGL(k_hist,    dim3(2048), dim3(256), 0, stream, x, hist, n);
        hipLaunchKernelGGL(k_scan,    dim3(1),    dim3(256), 0, stream, hist);
        hipLaunchKernelGGL(k_scatter, dim3(2048), dim3(256), 0, stream, x, hist, perm, n);
        hipLaunchKernelGGL(k_gatherx, dim3(2048), dim3(256), 0, stream, x, perm, xs, n);

        hipLaunchKernelGGL(hashenc_lo, dim3(bpl * LO_LEVELS), dim3(256),
                           0, stream, xs, perm, tables, out, n, bpl);
    } else {
        const int blocks = ((n + 511) / 512) * 8;
        hipLaunchKernelGGL(hashenc_lvl, dim3(blocks), dim3(256), 0, stream,
                           x, tables, out, n, 0);
        hipLaunchKernelGGL(hashenc_lvl, dim3(blocks), dim3(256), 0, stream,
                           x, tables, out, n, 8);
    }
}

// Round 10
// 1596.332 us; speedup vs baseline: 1.7329x; 1.2363x over previous
//
#include <hip/hip_runtime.h>
#include <cstdint>

#define NLEV 16
#define HMAP (1u << 19)
#define HMASK (HMAP - 1u)

typedef float f32x2 __attribute__((ext_vector_type(2)));

// res[l] = int(16 * 1.5**l), exact in double
__device__ __constant__ int RES_C[NLEV] = {16, 24, 36, 54, 81, 121, 182, 273,
                                           410, 615, 922, 1383, 2075, 3113, 4670, 7006};

// Shared body: encode 2 points at one level, batched gathers.
__device__ __forceinline__ void enc2(const float* __restrict__ x,
                                     const float2* __restrict__ tl,
                                     float* __restrict__ out,
                                     int lvl, int p0raw, int p1raw, int n) {
    const float rf = (float)RES_C[lvl];
    const float HI = (float)(1.0 - 1e-6);  // same double->f32 rounding as JAX

    uint32_t idx[2][8];
    float fx[2], fy[2], fz[2];
    int   pidx[2];
    bool  valid[2];
    const int praw[2] = {p0raw, p1raw};

    #pragma unroll
    for (int t = 0; t < 2; ++t) {
        int p = praw[t];
        valid[t] = (p < n);
        p = p < n ? p : (n - 1);  // clamp: compute harmless, store predicated
        pidx[t] = p;

        float px = __builtin_nontemporal_load(x + 3 * (size_t)p + 0);
        float py = __builtin_nontemporal_load(x + 3 * (size_t)p + 1);
        float pz = __builtin_nontemporal_load(x + 3 * (size_t)p + 2);
        px = fminf(fmaxf(px, 0.0f), HI);
        py = fminf(fmaxf(py, 0.0f), HI);
        pz = fminf(fmaxf(pz, 0.0f), HI);

        const float xs = px * rf, ys = py * rf, zs = pz * rf;
        const float xf = floorf(xs), yf = floorf(ys), zf = floorf(zs);
        fx[t] = xs - xf;  fy[t] = ys - yf;  fz[t] = zs - zf;

        const uint32_t cx = (uint32_t)(int)xf;
        const uint32_t cy = (uint32_t)(int)yf;
        const uint32_t cz = (uint32_t)(int)zf;
        const uint32_t hx[2] = {cx * 73856093u, cx * 73856093u + 73856093u};
        const uint32_t hy[2] = {cy * 19349663u, cy * 19349663u + 19349663u};
        const uint32_t hz[2] = {cz * 83492791u, cz * 83492791u + 83492791u};

        #pragma unroll
        for (int c = 0; c < 8; ++c) {
            const int ox = (c >> 2) & 1;
            const int oy = (c >> 1) & 1;
            const int oz = c & 1;
            idx[t][c] = (hx[ox] ^ hy[oy] ^ hz[oz]) & HMASK;
        }
    }

    // Batch all 16 gathers for max memory-level parallelism.
    float2 v[2][8];
    #pragma unroll
    for (int t = 0; t < 2; ++t)
        #pragma unroll
        for (int c = 0; c < 8; ++c)
            v[t][c] = tl[idx[t][c]];

    #pragma unroll
    for (int t = 0; t < 2; ++t) {
        const float wxa[2] = {1.0f - fx[t], fx[t]};
        const float wya[2] = {1.0f - fy[t], fy[t]};
        const float wza[2] = {1.0f - fz[t], fz[t]};
        float fa = 0.0f, fb = 0.0f;
        #pragma unroll
        for (int c = 0; c < 8; ++c) {
            const int ox = (c >> 2) & 1;
            const int oy = (c >> 1) & 1;
            const int oz = c & 1;
            const float wt = (wxa[ox] * wya[oy]) * wza[oz];
            fa = fmaf(wt, v[t][c].x, fa);
            fb = fmaf(wt, v[t][c].y, fb);
        }
        if (valid[t]) {
            f32x2 ov = {fa, fb};
            f32x2* dst = (f32x2*)(out + (size_t)pidx[t] * (NLEV * 2) + lvl * 2);
            __builtin_nontemporal_store(ov, dst);
        }
    }
}

// Launch A: levels 8-15, one level per XCD (all heavy, naturally balanced).
__global__ __launch_bounds__(256, 4)
void hashenc_hi(const float* __restrict__ x,
                const float* __restrict__ tables,
                float* __restrict__ out, int n) {
    const int lvl   = 8 + (int)(blockIdx.x & 7);
    const int chunk = (int)(blockIdx.x >> 3);
    const int tid   = (int)threadIdx.x;
    const float2* __restrict__ tl = (const float2*)tables + (size_t)lvl * HMAP;
    const int base = chunk * 512;
    enc2(x, tl, out, lvl, base + tid, base + 256 + tid, n);
}

// Launch B: levels 0-7 load-balanced. Heavy levels 2-7 are cut into 48 slices
// of 256K points, dealt 6-per-XCD in contiguous runs (<=2 tables per XCD,
// temporally separated). Cheap levels 0-1 split 8-ways as trailing units.
__global__ __launch_bounds__(256, 4)
void hashenc_lo(const float* __restrict__ x,
                const float* __restrict__ tables,
                float* __restrict__ out, int n) {
    const int xcd  = (int)(blockIdx.x & 7);
    const int rest = (int)(blockIdx.x >> 3);  // 0..4095
    const int u    = rest >> 9;               // unit 0..7
    const int pos  = rest & 511;              // 0..511
    int lvl, slice;
    if (u < 6) {                       // heavy: global slice s in [0,48)
        const int s = xcd * 6 + u;
        lvl   = 2 + (s >> 3);
        slice = s & 7;
    } else {                           // cheap rider: level u-6, slice = xcd
        lvl   = u - 6;
        slice = xcd;
    }
    const int tid  = (int)threadIdx.x;
    const float2* __restrict__ tl = (const float2*)tables + (size_t)lvl * HMAP;
    const int base = slice * 262144 + pos * 512;
    enc2(x, tl, out, lvl, base + tid, base + 256 + tid, n);
}

extern "C" void kernel_launch(void* const* d_in, const int* in_sizes, int n_in,
                              void* d_out, int out_size, void* d_ws, size_t ws_size,
                              hipStream_t stream) {
    const float* x      = (const float*)d_in[0];
    const float* tables = (const float*)d_in[1];
    float* out          = (float*)d_out;
    const int n = in_sizes[0] / 3;   // 2^21 for this problem
    const int blocksA = ((n + 511) / 512) * 8;
    hipLaunchKernelGGL(hashenc_hi, dim3(blocksA), dim3(256), 0, stream,
                       x, tables, out, n);
    hipLaunchKernelGGL(hashenc_lo, dim3(32768), dim3(256), 0, stream,
                       x, tables, out, n);
}